// Round 2
// baseline (220.923 us; speedup 1.0000x reference)
//
#include <hip/hip_runtime.h>
#include <math.h>

#define NB 8
#define NGRID 343
#define HID 64
#define NPATH 20

// ---------------- compile-time Clifford tables (Cl(3,0), blade order:
// 1, e1, e2, e3, e12, e13, e23, e123 — matches reference combinations order) ---
struct Tab {
  int prod_idx[8][8];  // blade index of product blade_k * blade_m
  int prod_sgn[8][8];  // sign of that product
  int pid[4][4][4];    // path id for (grade_left, grade_out, grade_right), 20 = dead
  int grade[8];        // grade of blade idx
  int kk_idx[8][8];    // for (l,m): unique k with prod(k,m) = +-l
  int kk_sgn[8][8];    // C[kk, l, m]
};

constexpr Tab make_tab() {
  Tab t{};
  int mask[8]  = {0,1,2,4,3,5,6,7};  // blade idx -> bitmask
  int idxof[8] = {0,1,2,4,3,5,6,7};  // bitmask -> blade idx
  for (int k = 0; k < 8; ++k) {
    int g = 0;
    for (int b = 0; b < 3; ++b) g += (mask[k] >> b) & 1;
    t.grade[k] = g;
  }
  for (int k = 0; k < 8; ++k)
    for (int m = 0; m < 8; ++m) {
      int A = mask[k], B = mask[m];
      t.prod_idx[k][m] = idxof[A ^ B];
      int c = 0;
      for (int i = 0; i < 3; ++i)
        if ((B >> i) & 1)
          for (int j = i + 1; j < 3; ++j)
            if ((A >> j) & 1) c++;
      t.prod_sgn[k][m] = (c & 1) ? -1 : 1;
    }
  int pc = 0;
  for (int a = 0; a < 4; ++a)
    for (int b = 0; b < 4; ++b)
      for (int c = 0; c < 4; ++c) {
        bool ok = false;
        for (int k = 0; k < 8; ++k)
          for (int m = 0; m < 8; ++m)
            if (t.grade[k] == a && t.grade[m] == c &&
                t.grade[t.prod_idx[k][m]] == b)
              ok = true;
        t.pid[a][b][c] = ok ? pc++ : NPATH;
      }
  for (int l = 0; l < 8; ++l)
    for (int m = 0; m < 8; ++m)
      for (int k = 0; k < 8; ++k)
        if (t.prod_idx[k][m] == l) {
          t.kk_idx[l][m] = k;
          t.kk_sgn[l][m] = t.prod_sgn[k][m];
        }
  return t;
}
constexpr Tab TB = make_tab();

// ---------------- workspace layout (floats) ----------------
// lin0_t [4][33][64]          @ 0        (8448)
// lins_t [3][4][64][64]       @ 8448     (49152)   ([l][g][i][hh])
// gps_t  [4][64][20][64]      @ 57600    (327680)  ([l][i][p][o])
// outW_t [4][64][1024]        @ 385280   (262144)  ([g][i][oc])
// k_ws   [1024][343][8]       @ 647424   (2809856)
#define OFF_LIN0T 0
#define OFF_LINST 8448
#define OFF_GPST  57600
#define OFF_OUTWT 385280
#define OFF_KWS   647424

// ---------------- kernel 0: weight transpose ----------------
__global__ void ccs_prep_kernel(const float* __restrict__ lin0_W,
                                const float* __restrict__ lins_W,
                                const float* __restrict__ gps_w,
                                const float* __restrict__ out_W,
                                float* __restrict__ ws) {
  const int TOT = 8448 + 49152 + 327680 + 262144;
  for (int d = blockIdx.x * blockDim.x + threadIdx.x; d < TOT;
       d += gridDim.x * blockDim.x) {
    float v;
    if (d < 8448) {
      int idx = d;
      int hh = idx & 63, ch = (idx >> 6) % 33, g = (idx >> 6) / 33;
      v = lin0_W[(g * 64 + hh) * 33 + ch];
    } else if (d < 8448 + 49152) {
      int idx = d - OFF_LINST;
      int hh = idx & 63, i = (idx >> 6) & 63, g = (idx >> 12) & 3, l = idx >> 14;
      v = lins_W[((l * 4 + g) * 64 + hh) * 64 + i];
    } else if (d < 8448 + 49152 + 327680) {
      int idx = d - OFF_GPST;
      int o = idx & 63, p = (idx >> 6) % 20, i = ((idx >> 6) / 20) & 63,
          l = idx / 81920;
      v = gps_w[((l * 64 + o) * 64 + i) * 20 + p];
    } else {
      int idx = d - OFF_OUTWT;
      int oc = idx & 1023, i = (idx >> 10) & 63, g = idx >> 16;
      v = out_W[(g * 1024 + oc) * 64 + i];
    }
    ws[d] = v;
  }
}

// ---------------- kernel 1: per-grid-point network ----------------
__launch_bounds__(256)
__global__ void ccs_net_kernel(const float* __restrict__ condition,
                               const float* __restrict__ rel_pos_sigma,
                               const float* __restrict__ lin0_b,
                               const float* __restrict__ act0_a,
                               const float* __restrict__ act0_b,
                               const float* __restrict__ lins_b,
                               const float* __restrict__ acts_a,
                               const float* __restrict__ acts_b,
                               const float* __restrict__ out_b,
                               const float* __restrict__ shell_sigma,
                               const float* __restrict__ ws,
                               float* __restrict__ kws) {
  const float* lin0t = ws + OFF_LIN0T;
  const float* linst = ws + OFF_LINST;
  const float* gpst  = ws + OFF_GPST;
  const float* outwt = ws + OFF_OUTWT;

  __shared__ float xb[33 * 8];
  __shared__ float F0[64 * 8];
  __shared__ float F1[64 * 8];
  __shared__ float part[4 * 64 * 8];

  const int n = blockIdx.x;
  const int tid = threadIdx.x;
  const int iz = n % 7, iy = (n / 7) % 7, ix = n / 49;
  const float px = (float)ix - 3.f, py = (float)iy - 3.f, pz = (float)iz - 3.f;
  const float q = px * px + py * py + pz * pz;
  const float sig = rel_pos_sigma[0];
  const float scal = expf(-q / (2.f * sig * sig));

  // NOTE: 33*8 = 264 > blockDim (256) — must stride, a plain `if (tid<264)`
  // leaves entries 256..263 (condition channel 31) uninitialized.
  for (int t = tid; t < 264; t += 256) {
    int ch = t >> 3, b = t & 7;
    float v;
    if (ch == 0)
      v = (b == 0) ? scal : (b == 1) ? px : (b == 2) ? py : (b == 3) ? pz : 0.f;
    else
      v = condition[(ch - 1) * 8 + b];
    xb[t] = v;
  }
  __syncthreads();

  const int hh = tid & 63;
  const int brow = tid >> 6;

  // ---- lin0: xb (33 ch) -> F0 raw ----
  #pragma unroll
  for (int rep = 0; rep < 2; ++rep) {
    int b = brow + 4 * rep;
    int g = TB.grade[b];
    float acc = (b == 0) ? lin0_b[hh] : 0.f;
    const float* wrow = lin0t + g * 33 * 64 + hh;
    #pragma unroll
    for (int ch = 0; ch < 33; ++ch)
      acc = fmaf(wrow[ch * 64], xb[ch * 8 + b], acc);
    F0[hh * 8 + b] = acc;
  }
  __syncthreads();

  // ---- helpers ----
  auto silu = [&](const float* src, float* dst, const float* aa,
                  const float* bb) {
    #pragma unroll
    for (int rep = 0; rep < 2; ++rep) {
      int b = brow + 4 * rep;
      int g = TB.grade[b];
      int s0 = (g == 0) ? 0 : (g == 1) ? 1 : (g == 2) ? 4 : 7;
      int cnt = (g == 0 || g == 3) ? 1 : 3;
      float qg = 0.f;
      for (int u = 0; u < cnt; ++u) {
        float v = src[hh * 8 + s0 + u];
        qg = fmaf(v, v, qg);
      }
      float z = fmaf(aa[hh * 4 + g], qg, bb[hh * 4 + g]);
      float gate = 1.f / (1.f + expf(-z));
      dst[hh * 8 + b] = src[hh * 8 + b] * gate;
    }
  };

  auto lin = [&](const float* src, float* dst, const float* wt,
                 const float* bias) {
    #pragma unroll
    for (int rep = 0; rep < 2; ++rep) {
      int b = brow + 4 * rep;
      int g = TB.grade[b];
      float acc = (b == 0) ? bias[hh] : 0.f;
      const float* wrow = wt + g * 64 * 64 + hh;
      #pragma unroll
      for (int i = 0; i < 64; ++i)
        acc = fmaf(wrow[i * 64], src[i * 8 + b], acc);
      dst[hh * 8 + b] = acc;
    }
  };

  auto gp = [&](const float* src, float* dst, const float* wl) {
    const int o = tid & 63;
    const int isub = tid >> 6;
    float facc[8];
    #pragma unroll
    for (int j = 0; j < 8; ++j) facc[j] = 0.f;
    for (int it = 0; it < 16; ++it) {
      int i = isub * 16 + it;
      float x8[8];
      #pragma unroll
      for (int b = 0; b < 8; ++b) x8[b] = src[i * 8 + b];
      const float* wb = wl + i * 20 * 64 + o;
      float wp[20];
      #pragma unroll
      for (int p = 0; p < 20; ++p) wp[p] = wb[p * 64];
      #pragma unroll
      for (int k = 0; k < 8; ++k) {
        #pragma unroll
        for (int m = 0; m < 8; ++m) {
          const int j = TB.prod_idx[k][m];
          const int p = TB.pid[TB.grade[k]][TB.grade[j]][TB.grade[m]];
          float tp = x8[k] * x8[m];
          if (TB.prod_sgn[k][m] > 0)
            facc[j] = fmaf(tp, wp[p], facc[j]);
          else
            facc[j] = fmaf(-tp, wp[p], facc[j]);
        }
      }
    }
    #pragma unroll
    for (int j = 0; j < 8; ++j) part[(isub * 64 + o) * 8 + j] = facc[j];
    __syncthreads();
    #pragma unroll
    for (int rep = 0; rep < 2; ++rep) {
      int idx = tid + rep * 256;
      float s = part[idx] + part[idx + 512] + part[idx + 1024] +
                part[idx + 1536];
      dst[idx] = s * 0.125f;
    }
    __syncthreads();
  };

  // ---- layer 0 ----
  silu(F0, F1, act0_a, act0_b);
  __syncthreads();
  gp(F1, F0, gpst + 0);  // features now in F0

  // ---- layers 1..3 ----
  float* f = F0;
  float* g_ = F1;
  for (int l = 0; l < 3; ++l) {
    lin(f, g_, linst + l * 16384, lins_b + l * 64);
    __syncthreads();
    silu(g_, f, acts_a + l * 256, acts_b + l * 256);
    __syncthreads();
    gp(f, g_, gpst + (l + 1) * 81920);  // result in g_
    float* t = f; f = g_; g_ = t;       // features in f
  }

  // ---- output linear + shell ----
  const float FACTOR = 1.0f / sqrtf(343.0f);
  #pragma unroll
  for (int r = 0; r < 4; ++r) {
    int oc = tid + r * 256;
    float acc[8];
    #pragma unroll
    for (int b = 0; b < 8; ++b) acc[b] = 0.f;
    acc[0] = out_b[oc];
    #pragma unroll 8
    for (int i = 0; i < 64; ++i) {
      float w0 = outwt[(0 * 64 + i) * 1024 + oc];
      float w1 = outwt[(1 * 64 + i) * 1024 + oc];
      float w2 = outwt[(2 * 64 + i) * 1024 + oc];
      float w3 = outwt[(3 * 64 + i) * 1024 + oc];
      const float* h = f + i * 8;
      acc[0] = fmaf(w0, h[0], acc[0]);
      acc[1] = fmaf(w1, h[1], acc[1]);
      acc[2] = fmaf(w1, h[2], acc[2]);
      acc[3] = fmaf(w1, h[3], acc[3]);
      acc[4] = fmaf(w2, h[4], acc[4]);
      acc[5] = fmaf(w2, h[5], acc[5]);
      acc[6] = fmaf(w2, h[6], acc[6]);
      acc[7] = fmaf(w3, h[7], acc[7]);
    }
    float out8[8];
    #pragma unroll
    for (int b = 0; b < 8; ++b) {
      float ss = shell_sigma[oc * 8 + b];
      out8[b] = acc[b] * expf(-q / (ss * ss)) * FACTOR;
    }
    float4* dst = (float4*)(kws + ((size_t)oc * 343 + n) * 8);
    dst[0] = make_float4(out8[0], out8[1], out8[2], out8[3]);
    dst[1] = make_float4(out8[4], out8[5], out8[6], out8[7]);
  }
}

// ---------------- kernel 2: Cayley expansion to output ----------------
__launch_bounds__(64)
__global__ void ccs_expand_kernel(const float* __restrict__ cayley_w,
                                  const float* __restrict__ kws,
                                  float* __restrict__ out) {
  const int oi = blockIdx.x;  // o*32 + i
  const int o = oi >> 5, i = oi & 31;
  const int n = blockIdx.y * 64 + threadIdx.x;
  if (n >= NGRID) return;
  float cw[20];
  #pragma unroll
  for (int p = 0; p < 20; ++p) cw[p] = cayley_w[oi * 20 + p];
  const float* kp = kws + ((size_t)oi * 343 + n) * 8;
  float k8[8];
  #pragma unroll
  for (int b = 0; b < 8; ++b) k8[b] = kp[b];
  #pragma unroll
  for (int l = 0; l < 8; ++l) {
    #pragma unroll
    for (int m = 0; m < 8; ++m) {
      const int kk = TB.kk_idx[l][m];
      const int p = TB.pid[TB.grade[kk]][TB.grade[l]][TB.grade[m]];
      float v = k8[kk] * cw[p];
      if (TB.kk_sgn[l][m] < 0) v = -v;
      out[((size_t)((o * 8 + l) * 256 + i * 8 + m)) * 343 + n] = v;
    }
  }
}

extern "C" void kernel_launch(void* const* d_in, const int* in_sizes, int n_in,
                              void* d_out, int out_size, void* d_ws,
                              size_t ws_size, hipStream_t stream) {
  const float* condition     = (const float*)d_in[0];
  const float* rel_pos_sigma = (const float*)d_in[1];
  const float* cayley_w      = (const float*)d_in[2];
  const float* lin0_W        = (const float*)d_in[3];
  const float* lin0_b        = (const float*)d_in[4];
  const float* act0_a        = (const float*)d_in[5];
  const float* act0_b        = (const float*)d_in[6];
  const float* gps_w         = (const float*)d_in[7];
  const float* lins_W        = (const float*)d_in[8];
  const float* lins_b        = (const float*)d_in[9];
  const float* acts_a        = (const float*)d_in[10];
  const float* acts_b        = (const float*)d_in[11];
  const float* out_W         = (const float*)d_in[12];
  const float* out_b         = (const float*)d_in[13];
  const float* shell_sigma   = (const float*)d_in[14];

  float* ws = (float*)d_ws;
  float* kws = ws + OFF_KWS;
  float* out = (float*)d_out;

  ccs_prep_kernel<<<dim3(640), dim3(256), 0, stream>>>(lin0_W, lins_W, gps_w,
                                                       out_W, ws);
  ccs_net_kernel<<<dim3(343), dim3(256), 0, stream>>>(
      condition, rel_pos_sigma, lin0_b, act0_a, act0_b, lins_b, acts_a, acts_b,
      out_b, shell_sigma, ws, kws);
  ccs_expand_kernel<<<dim3(1024, 6), dim3(64), 0, stream>>>(cayley_w, kws, out);
}